// Round 17
// baseline (144.860 us; speedup 1.0000x reference)
//
#include <hip/hip_runtime.h>

typedef __attribute__((ext_vector_type(8)))  short short8;
typedef __attribute__((ext_vector_type(4)))  short short4v;
typedef __attribute__((ext_vector_type(4)))  float f32x4;
typedef __attribute__((ext_vector_type(16))) float f32x16;

__device__ inline short f2bf(float f) {
  unsigned u = __float_as_uint(f);
  u += 0x7fffu + ((u >> 16) & 1u);   // RNE to bf16
  return (short)(u >> 16);
}

// Barrier draining only LDS ops (lgkmcnt) -- global stores stay in flight.
__device__ __forceinline__ void barrier_lgkm() {
  asm volatile("s_waitcnt lgkmcnt(0)" ::: "memory");
  __builtin_amdgcn_s_barrier();
}

// ---------------- fused weight conversion ----------------
// blocks [0,1024): w1 fp32->bf16 linear (one short4v per thread)
// blocks [1024,3072): w2 fp32->bf16 fragment-major:
//   w2f[l][stile(32)][kstep(16)][lane(64)][8]; lane=(khalf<<5)|srow;
//   s=stile*32+srow; r=kstep*16+khalf*8+e.
__global__ void cvt_all(const float* __restrict__ w1, short* __restrict__ w1b,
                        const float* __restrict__ w2, short* __restrict__ w2f) {
  if (blockIdx.x < 1024) {
    int i = blockIdx.x * 256 + threadIdx.x;          // covers n4 = 262144 exactly
    f32x4 v = ((const f32x4*)w1)[i];
    short4v o;
    o[0] = f2bf(v[0]); o[1] = f2bf(v[1]); o[2] = f2bf(v[2]); o[3] = f2bf(v[3]);
    ((short4v*)w1b)[i] = o;
    return;
  }
  int t = (blockIdx.x - 1024) * 256 + threadIdx.x;   // 0 .. 524287
  int lane  = t & 63;
  int f     = t >> 6;
  int kh    = f & 1;
  int ck    = (f >> 1) & 7;
  int stile = (f >> 4) & 31;
  int l     = f >> 9;
  int lrow = lane & 31, khalf = lane >> 5;
  int s = stile * 32 + lrow;
  int r = ck * 32 + kh * 16 + khalf * 8;
  const float* src = w2 + (size_t)(l * 1024 + s) * 256 + r;
  f32x4 lo = *(const f32x4*)src;
  f32x4 hi = *(const f32x4*)(src + 4);
  short8 o;
  o[0]=f2bf(lo[0]); o[1]=f2bf(lo[1]); o[2]=f2bf(lo[2]); o[3]=f2bf(lo[3]);
  o[4]=f2bf(hi[0]); o[5]=f2bf(hi[1]); o[6]=f2bf(hi[2]); o[7]=f2bf(hi[3]);
  ((short8*)w2f)[t] = o;
}

// ---------------- stage 1: out1[b,k,q] = sum_p x[b,k*256+p] * w1[k,q,p] ----------------
// x tile staged in LDS with coalesced loads; fragments read from LDS (swizzled).
// Output stored A-fragment-major: interf[btile(128)][l(16)][kstep(16)][lane(64)][8].
__global__ __launch_bounds__(256) void stage1_kernel(
    const float* __restrict__ x, const short* __restrict__ w1b, short* __restrict__ interf) {
  __shared__ __align__(16) char smem[65536];   // phase 1: x tile (64KB); phase 2: C buf (32KB)
  const int tid  = threadIdx.x;
  const int lane = tid & 63;
  const int wq   = tid >> 6;            // wave 0..3 -> q range
  const int b0   = blockIdx.x * 64;
  const int k    = blockIdx.y;          // 0..15
  const int q0w  = wq * 64;
  const int lr   = lane & 15;
  const int kid  = lane >> 4;           // 0..3

  // ---- stage x tile: 16 coalesced f32x4 per thread ----
  #pragma unroll
  for (int i = 0; i < 16; ++i) {
    int idx = i * 256 + tid;
    int row = idx >> 6, seg = idx & 63;
    f32x4 v = *(const f32x4*)(x + (size_t)(b0 + row) * 4096 + k * 256 + seg * 4);
    int byte = (row * 1024 + seg * 16) ^ ((row & 7) << 4);
    *(f32x4*)(smem + byte) = v;
  }
  barrier_lgkm();

  f32x4 acc[4][4] = {};
  const short* wbase = w1b + k * 65536 + (q0w + lr) * 256 + kid * 8;

  #pragma unroll
  for (int kk = 0; kk < 256; kk += 32) {
    short8 a[4], b[4];
    #pragma unroll
    for (int mt = 0; mt < 4; ++mt) {
      int row = mt * 16 + lr;
      int u = row * 1024 + kid * 32 + kk * 4;
      int s = (row & 7) << 4;
      f32x4 lo = *(const f32x4*)(smem + (u ^ s));
      f32x4 hi = *(const f32x4*)(smem + ((u + 16) ^ s));
      short8 av;
      av[0] = f2bf(lo[0]); av[1] = f2bf(lo[1]); av[2] = f2bf(lo[2]); av[3] = f2bf(lo[3]);
      av[4] = f2bf(hi[0]); av[5] = f2bf(hi[1]); av[6] = f2bf(hi[2]); av[7] = f2bf(hi[3]);
      a[mt] = av;
    }
    #pragma unroll
    for (int nt = 0; nt < 4; ++nt)
      b[nt] = *(const short8*)(wbase + nt * 16 * 256 + kk);
    #pragma unroll
    for (int mt = 0; mt < 4; ++mt)
      #pragma unroll
      for (int nt = 0; nt < 4; ++nt)
        acc[mt][nt] = __builtin_amdgcn_mfma_f32_16x16x32_bf16(a[mt], b[nt], acc[mt][nt], 0, 0, 0);
  }

  barrier_lgkm();   // x-tile LDS reads done before C-transpose overwrites smem

  // acc -> LDS transpose. value(b=blocal, q) with l=q&15=lr, rlocal=q>>4=wq*4+nt.
  #pragma unroll
  for (int mt = 0; mt < 4; ++mt) {
    #pragma unroll
    for (int j = 0; j < 4; ++j) {
      int blocal = mt * 16 + kid * 4 + j;            // row = (lane>>4)*4 + reg
      int byte = (blocal * 512 + lr * 32 + wq * 8) ^ ((blocal & 7) << 4);
      short4v v;
      #pragma unroll
      for (int nt = 0; nt < 4; ++nt) v[nt] = f2bf(acc[mt][nt][j]);
      *(short4v*)(smem + byte) = v;
    }
  }
  barrier_lgkm();

  // fragment-major store: 8 iters x 4 waves = 32 frags of 1KB, fully coalesced
  const int brow = lane & 31, khalf = lane >> 5;
  #pragma unroll
  for (int j = 0; j < 8; ++j) {
    int f   = j * 4 + wq;
    int btl = f >> 4, l = f & 15;
    int blc = btl * 32 + brow;
    int rbyte = (blc * 512 + l * 32 + khalf * 16) ^ ((blc & 7) << 4);
    short8 v = *(const short8*)(smem + rbyte);
    size_t off = (((size_t)(blockIdx.x * 2 + btl) * 16 + l) * 16 + k) * 512 + lane * 8;
    *(short8*)(interf + off) = v;
  }
}

// ---------------- stage 2: out[b][s*16+l] = sum_r inter[b][l][r] * w2[l][s][r] ----------------
// ILP-deep variant: 512 threads = 8 waves; wave w owns the l-PAIR {w, w+8},
// computing both 64b x 64s tiles (acc = 128 regs). launch_bounds(512,2) ->
// 256 unified regs/wave: ~100 VGPRs free for load pipelining (R12's 1024-thr
// version capped each wave at ~3 in-flight loads out of 64 -- the K-loop was
// register-starved latency-bound: MfmaUtil 8%, everything idle). 8 loads + 8
// MFMA per kstep (1:1). Block still covers all 16 l -> full 64B output lines.
// Decode, NT stores, lgkm barriers, 64KB clds epilogue unchanged from R16.
__global__ __launch_bounds__(512, 2) void stage2_kernel(
    const short* __restrict__ interf, const short* __restrict__ w2f, float* __restrict__ out) {
  __shared__ float clds[16 * 1024];      // 64KB C-transpose buffer
  const int tid  = threadIdx.x;
  const int lane = tid & 63;
  const int w    = tid >> 6;             // wave 0..7 -> l-pair {w, w+8}
  const int lrow = lane & 31;
  const int khalf = lane >> 5;

  const int L    = blockIdx.x;           // 0..1023; physical XCD = L & 7
  const int xcd  = L & 7;
  const int pos  = L >> 3;               // 0..127
  const int pass = pos >> 6;             // 0,1
  const int idx  = pos & 63;
  const int st   = idx & 15;             // fastest: row-contiguous write streams
  const int bt   = idx >> 4;             // 0..3 slow: A-slice stays hot in L2
  const int BBT  = xcd * 8 + pass * 4 + bt;   // 0..63
  const int BST  = st;                        // 0..15
  const int b0 = BBT * 64, s0 = BST * 64;

  // interf[btile][l][kstep][lane][8]: btile stride 131072, l stride 8192, kstep 512
  const short* ap = interf + (size_t)(BBT * 2) * 131072 + w * 8192 + lane * 8;
  // w2f[l][stile][kstep][lane][8]: l stride 262144, stile 8192, kstep 512
  const short* bp = w2f + (size_t)w * 262144 + (size_t)(BST * 2) * 8192 + lane * 8;

  f32x16 acc0[2][2] = {};   // l = w
  f32x16 acc1[2][2] = {};   // l = w + 8

  #pragma unroll
  for (int ks = 0; ks < 16; ++ks) {
    short8 a00 = *(const short8*)(ap + ks * 512);                    // l=w,   btile0
    short8 a01 = *(const short8*)(ap + 131072 + ks * 512);           // l=w,   btile1
    short8 a10 = *(const short8*)(ap + 65536 + ks * 512);            // l=w+8, btile0
    short8 a11 = *(const short8*)(ap + 65536 + 131072 + ks * 512);   // l=w+8, btile1
    short8 fb00 = *(const short8*)(bp + ks * 512);                   // l=w,   stile0
    short8 fb01 = *(const short8*)(bp + 8192 + ks * 512);            // l=w,   stile1
    short8 fb10 = *(const short8*)(bp + 2097152 + ks * 512);         // l=w+8, stile0
    short8 fb11 = *(const short8*)(bp + 2097152 + 8192 + ks * 512);  // l=w+8, stile1
    acc0[0][0] = __builtin_amdgcn_mfma_f32_32x32x16_bf16(a00, fb00, acc0[0][0], 0, 0, 0);
    acc0[0][1] = __builtin_amdgcn_mfma_f32_32x32x16_bf16(a00, fb01, acc0[0][1], 0, 0, 0);
    acc0[1][0] = __builtin_amdgcn_mfma_f32_32x32x16_bf16(a01, fb00, acc0[1][0], 0, 0, 0);
    acc0[1][1] = __builtin_amdgcn_mfma_f32_32x32x16_bf16(a01, fb01, acc0[1][1], 0, 0, 0);
    acc1[0][0] = __builtin_amdgcn_mfma_f32_32x32x16_bf16(a10, fb10, acc1[0][0], 0, 0, 0);
    acc1[0][1] = __builtin_amdgcn_mfma_f32_32x32x16_bf16(a10, fb11, acc1[0][1], 0, 0, 0);
    acc1[1][0] = __builtin_amdgcn_mfma_f32_32x32x16_bf16(a11, fb10, acc1[1][0], 0, 0, 0);
    acc1[1][1] = __builtin_amdgcn_mfma_f32_32x32x16_bf16(a11, fb11, acc1[1][1], 0, 0, 0);
  }

  // epilogue: 4 chunks of 16 rows; LDS [row16][col'] f32, col = scol*16 + l,
  // swizzle l-slot: l ^= ((scol&3)<<2) ^ (((row16>>2)&3)<<2)  (keeps f32x4 groups intact)
  #pragma unroll
  for (int c = 0; c < 4; ++c) {
    const int bt2 = c >> 1, rh = c & 1;
    #pragma unroll
    for (int stt = 0; stt < 2; ++stt) {
      int scol = stt * 32 + lrow;
      #pragma unroll
      for (int rr = 0; rr < 8; ++rr) {
        int row16 = (rr & 3) + 8 * (rr >> 2) + 4 * khalf;   // verified 32x32 C/D map (mod 16)
        int sw = ((scol & 3) << 2) ^ (((row16 >> 2) & 3) << 2);
        clds[row16 * 1024 + scol * 16 + (w ^ sw)]       = acc0[bt2][stt][rh * 8 + rr];
        clds[row16 * 1024 + scol * 16 + ((w + 8) ^ sw)] = acc1[bt2][stt][rh * 8 + rr];
      }
    }
    barrier_lgkm();   // LDS writes visible; global stores stay in flight
    #pragma unroll
    for (int p = 0; p < 8; ++p) {
      int idx2 = p * 512 + tid;            // 0..4095
      int row  = idx2 >> 8;                // 0..15
      int slot = idx2 & 255;
      int scol = slot >> 2, lq = slot & 3;
      int colx = scol * 16 + ((lq * 4) ^ ((scol & 3) << 2) ^ (((row >> 2) & 3) << 2));
      f32x4 v = *(const f32x4*)&clds[row * 1024 + colx];
      __builtin_nontemporal_store(
          v, (f32x4*)(out + (size_t)(b0 + c * 16 + row) * 16384
                          + (size_t)(s0 + scol) * 16 + lq * 4));
    }
    barrier_lgkm();   // LDS reads done before next chunk overwrites clds
  }
}

extern "C" void kernel_launch(void* const* d_in, const int* in_sizes, int n_in,
                              void* d_out, int out_size, void* d_ws, size_t ws_size,
                              hipStream_t stream) {
  const float* x  = (const float*)d_in[0];
  const float* w1 = (const float*)d_in[1];
  const float* w2 = (const float*)d_in[2];
  float* out = (float*)d_out;

  short* interf = (short*)d_ws;                          // 32 MB  (fragment-major)
  short* w1b    = (short*)((char*)d_ws + (32u << 20));   //  2 MB
  short* w2f    = (short*)((char*)d_ws + (34u << 20));   //  8 MB  (fragment-major)

  cvt_all<<<3072, 256, 0, stream>>>(w1, w1b, w2, w2f);
  stage1_kernel<<<dim3(64, 16), 256, 0, stream>>>(x, w1b, interf);
  stage2_kernel<<<1024, 512, 0, stream>>>(interf, w2f, out);
}

// Round 18
// 133.351 us; speedup vs baseline: 1.0863x; 1.0863x over previous
//
#include <hip/hip_runtime.h>

typedef __attribute__((ext_vector_type(8)))  short short8;
typedef __attribute__((ext_vector_type(4)))  short short4v;
typedef __attribute__((ext_vector_type(4)))  float f32x4;
typedef __attribute__((ext_vector_type(16))) float f32x16;

__device__ inline short f2bf(float f) {
  unsigned u = __float_as_uint(f);
  u += 0x7fffu + ((u >> 16) & 1u);   // RNE to bf16
  return (short)(u >> 16);
}

// Barrier draining only LDS ops (lgkmcnt) -- global stores stay in flight.
__device__ __forceinline__ void barrier_lgkm() {
  asm volatile("s_waitcnt lgkmcnt(0)" ::: "memory");
  __builtin_amdgcn_s_barrier();
}

// ---------------- fused weight conversion ----------------
// blocks [0,1024): w1 fp32->bf16 linear (one short4v per thread)
// blocks [1024,3072): w2 fp32->bf16 fragment-major:
//   w2f[l][stile(32)][kstep(16)][lane(64)][8]; lane=(khalf<<5)|srow;
//   s=stile*32+srow; r=kstep*16+khalf*8+e.
__global__ void cvt_all(const float* __restrict__ w1, short* __restrict__ w1b,
                        const float* __restrict__ w2, short* __restrict__ w2f) {
  if (blockIdx.x < 1024) {
    int i = blockIdx.x * 256 + threadIdx.x;          // covers n4 = 262144 exactly
    f32x4 v = ((const f32x4*)w1)[i];
    short4v o;
    o[0] = f2bf(v[0]); o[1] = f2bf(v[1]); o[2] = f2bf(v[2]); o[3] = f2bf(v[3]);
    ((short4v*)w1b)[i] = o;
    return;
  }
  int t = (blockIdx.x - 1024) * 256 + threadIdx.x;   // 0 .. 524287
  int lane  = t & 63;
  int f     = t >> 6;
  int kh    = f & 1;
  int ck    = (f >> 1) & 7;
  int stile = (f >> 4) & 31;
  int l     = f >> 9;
  int lrow = lane & 31, khalf = lane >> 5;
  int s = stile * 32 + lrow;
  int r = ck * 32 + kh * 16 + khalf * 8;
  const float* src = w2 + (size_t)(l * 1024 + s) * 256 + r;
  f32x4 lo = *(const f32x4*)src;
  f32x4 hi = *(const f32x4*)(src + 4);
  short8 o;
  o[0]=f2bf(lo[0]); o[1]=f2bf(lo[1]); o[2]=f2bf(lo[2]); o[3]=f2bf(lo[3]);
  o[4]=f2bf(hi[0]); o[5]=f2bf(hi[1]); o[6]=f2bf(hi[2]); o[7]=f2bf(hi[3]);
  ((short8*)w2f)[t] = o;
}

// ---------------- stage 1: out1[b,k,q] = sum_p x[b,k*256+p] * w1[k,q,p] ----------------
// x tile staged in LDS with coalesced loads; fragments read from LDS (swizzled).
// Output stored A-fragment-major: interf[btile(128)][l(16)][kstep(16)][lane(64)][8].
__global__ __launch_bounds__(256) void stage1_kernel(
    const float* __restrict__ x, const short* __restrict__ w1b, short* __restrict__ interf) {
  __shared__ __align__(16) char smem[65536];   // phase 1: x tile (64KB); phase 2: C buf (32KB)
  const int tid  = threadIdx.x;
  const int lane = tid & 63;
  const int wq   = tid >> 6;            // wave 0..3 -> q range
  const int b0   = blockIdx.x * 64;
  const int k    = blockIdx.y;          // 0..15
  const int q0w  = wq * 64;
  const int lr   = lane & 15;
  const int kid  = lane >> 4;           // 0..3

  // ---- stage x tile: 16 coalesced f32x4 per thread ----
  #pragma unroll
  for (int i = 0; i < 16; ++i) {
    int idx = i * 256 + tid;
    int row = idx >> 6, seg = idx & 63;
    f32x4 v = *(const f32x4*)(x + (size_t)(b0 + row) * 4096 + k * 256 + seg * 4);
    int byte = (row * 1024 + seg * 16) ^ ((row & 7) << 4);
    *(f32x4*)(smem + byte) = v;
  }
  barrier_lgkm();

  f32x4 acc[4][4] = {};
  const short* wbase = w1b + k * 65536 + (q0w + lr) * 256 + kid * 8;

  #pragma unroll
  for (int kk = 0; kk < 256; kk += 32) {
    short8 a[4], b[4];
    #pragma unroll
    for (int mt = 0; mt < 4; ++mt) {
      int row = mt * 16 + lr;
      int u = row * 1024 + kid * 32 + kk * 4;
      int s = (row & 7) << 4;
      f32x4 lo = *(const f32x4*)(smem + (u ^ s));
      f32x4 hi = *(const f32x4*)(smem + ((u + 16) ^ s));
      short8 av;
      av[0] = f2bf(lo[0]); av[1] = f2bf(lo[1]); av[2] = f2bf(lo[2]); av[3] = f2bf(lo[3]);
      av[4] = f2bf(hi[0]); av[5] = f2bf(hi[1]); av[6] = f2bf(hi[2]); av[7] = f2bf(hi[3]);
      a[mt] = av;
    }
    #pragma unroll
    for (int nt = 0; nt < 4; ++nt)
      b[nt] = *(const short8*)(wbase + nt * 16 * 256 + kk);
    #pragma unroll
    for (int mt = 0; mt < 4; ++mt)
      #pragma unroll
      for (int nt = 0; nt < 4; ++nt)
        acc[mt][nt] = __builtin_amdgcn_mfma_f32_16x16x32_bf16(a[mt], b[nt], acc[mt][nt], 0, 0, 0);
  }

  barrier_lgkm();   // x-tile LDS reads done before C-transpose overwrites smem

  // acc -> LDS transpose. value(b=blocal, q) with l=q&15=lr, rlocal=q>>4=wq*4+nt.
  #pragma unroll
  for (int mt = 0; mt < 4; ++mt) {
    #pragma unroll
    for (int j = 0; j < 4; ++j) {
      int blocal = mt * 16 + kid * 4 + j;            // row = (lane>>4)*4 + reg
      int byte = (blocal * 512 + lr * 32 + wq * 8) ^ ((blocal & 7) << 4);
      short4v v;
      #pragma unroll
      for (int nt = 0; nt < 4; ++nt) v[nt] = f2bf(acc[mt][nt][j]);
      *(short4v*)(smem + byte) = v;
    }
  }
  barrier_lgkm();

  // fragment-major store: 8 iters x 4 waves = 32 frags of 1KB, fully coalesced
  const int brow = lane & 31, khalf = lane >> 5;
  #pragma unroll
  for (int j = 0; j < 8; ++j) {
    int f   = j * 4 + wq;
    int btl = f >> 4, l = f & 15;
    int blc = btl * 32 + brow;
    int rbyte = (blc * 512 + l * 32 + khalf * 16) ^ ((blc & 7) << 4);
    short8 v = *(const short8*)(smem + rbyte);
    size_t off = (((size_t)(blockIdx.x * 2 + btl) * 16 + l) * 16 + k) * 512 + lane * 8;
    *(short8*)(interf + off) = v;
  }
}

// ---------------- stage 2: out[b][s*16+l] = sum_r inter[b][l][r] * w2[l][s][r] ----------------
// R16 structure (1024 thr, 16 waves = 16 l, 1:1 loads:MFMA K-loop, lgkm-only
// barriers, NT full-line stores) with the decode REVERSED: bt FASTEST, st slow.
// Rationale: with st fastest (R12), the 16 concurrent st-blocks of a bt-group
// touch all 8MB of w2f on a 4MB L2 -> B thrashes (FETCH 154MB vs 96 ideal).
// With bt fastest: active set = A-set 2MB (4 bt x 512KB, resident across all
// 16 sequential st-groups of a pass) + B-slice 512KB per st-group, streamed
// exactly once per XCD -> both fit L2 with room to spare.
__global__ __launch_bounds__(1024) void stage2_kernel(
    const short* __restrict__ interf, const short* __restrict__ w2f, float* __restrict__ out) {
  __shared__ float clds[16 * 1024];      // 64KB C-transpose buffer
  const int tid  = threadIdx.x;
  const int lane = tid & 63;
  const int l    = tid >> 6;             // wave = l
  const int lrow = lane & 31;
  const int khalf = lane >> 5;

  const int L    = blockIdx.x;           // 0..1023; physical XCD = L & 7
  const int xcd  = L & 7;
  const int pos  = L >> 3;               // 0..127
  const int pass = pos >> 6;             // 0,1
  const int idx  = pos & 63;
  const int bt   = idx & 3;              // FASTEST: 2MB A-set resident in L2
  const int st   = idx >> 2;             // 0..15 slow: 512KB B-slice per group,
                                         //        streamed once per XCD
  const int BBT  = xcd * 8 + pass * 4 + bt;   // 0..63
  const int BST  = st;                        // 0..15
  const int b0 = BBT * 64, s0 = BST * 64;

  // interf[btile][l][kstep][lane][8]: btile stride 131072, l stride 8192, kstep 512
  const short* ap = interf + (size_t)(BBT * 2) * 131072 + l * 8192 + lane * 8;
  // w2f[l][stile][kstep][lane][8]: l stride 262144, stile 8192, kstep 512
  const short* bp = w2f + (size_t)l * 262144 + (size_t)(BST * 2) * 8192 + lane * 8;

  f32x16 acc[2][2] = {};

  #pragma unroll
  for (int ks = 0; ks < 16; ++ks) {
    short8 a0 = *(const short8*)(ap + ks * 512);
    short8 a1 = *(const short8*)(ap + 131072 + ks * 512);
    short8 b0v = *(const short8*)(bp + ks * 512);
    short8 b1v = *(const short8*)(bp + 8192 + ks * 512);
    acc[0][0] = __builtin_amdgcn_mfma_f32_32x32x16_bf16(a0, b0v, acc[0][0], 0, 0, 0);
    acc[0][1] = __builtin_amdgcn_mfma_f32_32x32x16_bf16(a0, b1v, acc[0][1], 0, 0, 0);
    acc[1][0] = __builtin_amdgcn_mfma_f32_32x32x16_bf16(a1, b0v, acc[1][0], 0, 0, 0);
    acc[1][1] = __builtin_amdgcn_mfma_f32_32x32x16_bf16(a1, b1v, acc[1][1], 0, 0, 0);
  }

  // epilogue: 4 chunks of 16 rows; LDS [row16][col'] f32, col = scol*16 + l,
  // swizzle l-slot: l ^= ((scol&3)<<2) ^ (((row16>>2)&3)<<2)  (keeps f32x4 groups intact)
  #pragma unroll
  for (int c = 0; c < 4; ++c) {
    const int bt2 = c >> 1, rh = c & 1;
    #pragma unroll
    for (int stt = 0; stt < 2; ++stt) {
      int scol = stt * 32 + lrow;
      #pragma unroll
      for (int rr = 0; rr < 8; ++rr) {
        int row16 = (rr & 3) + 8 * (rr >> 2) + 4 * khalf;   // verified 32x32 C/D map (mod 16)
        int colx = scol * 16 + (l ^ ((scol & 3) << 2) ^ (((row16 >> 2) & 3) << 2));
        clds[row16 * 1024 + colx] = acc[bt2][stt][rh * 8 + rr];
      }
    }
    barrier_lgkm();   // LDS writes visible; global stores stay in flight
    #pragma unroll
    for (int p = 0; p < 4; ++p) {
      int idx2 = p * 1024 + tid;
      int row  = idx2 >> 8;                // 0..15
      int slot = idx2 & 255;
      int scol = slot >> 2, lq = slot & 3;
      int colx = scol * 16 + ((lq * 4) ^ ((scol & 3) << 2) ^ (((row >> 2) & 3) << 2));
      f32x4 v = *(const f32x4*)&clds[row * 1024 + colx];
      __builtin_nontemporal_store(
          v, (f32x4*)(out + (size_t)(b0 + c * 16 + row) * 16384
                          + (size_t)(s0 + scol) * 16 + lq * 4));
    }
    barrier_lgkm();   // LDS reads done before next chunk overwrites clds
  }
}

extern "C" void kernel_launch(void* const* d_in, const int* in_sizes, int n_in,
                              void* d_out, int out_size, void* d_ws, size_t ws_size,
                              hipStream_t stream) {
  const float* x  = (const float*)d_in[0];
  const float* w1 = (const float*)d_in[1];
  const float* w2 = (const float*)d_in[2];
  float* out = (float*)d_out;

  short* interf = (short*)d_ws;                          // 32 MB  (fragment-major)
  short* w1b    = (short*)((char*)d_ws + (32u << 20));   //  2 MB
  short* w2f    = (short*)((char*)d_ws + (34u << 20));   //  8 MB  (fragment-major)

  cvt_all<<<3072, 256, 0, stream>>>(w1, w1b, w2, w2f);
  stage1_kernel<<<dim3(64, 16), 256, 0, stream>>>(x, w1b, interf);
  stage2_kernel<<<1024, 1024, 0, stream>>>(interf, w2f, out);
}